// Round 1
// baseline (219.773 us; speedup 1.0000x reference)
//
#include <hip/hip_runtime.h>

// LTC cell: B=1024 batches, I=128 sensory inputs, N=256 neurons, 6 unfolds.
// Pipeline: pack (fold sigma*log2e etc into float4) -> sensory sums -> 6x step.
// All compute-bound on v_exp_f32/v_rcp_f32; weights register-reused across a
// batch-tile of 8 to keep L2 traffic ~768MB << VALU time.

#define LOG2E 1.44269504088896340f

constexpr int Bn = 1024;
constexpr int In = 128;
constexpr int Nn = 256;
constexpr int UNFOLDS = 6;

#if __has_builtin(__builtin_amdgcn_exp2f)
#define EXP2F(x) __builtin_amdgcn_exp2f(x)
#else
#define EXP2F(x) __exp2f(x)
#endif
#if __has_builtin(__builtin_amdgcn_rcpf)
#define RCPF(x) __builtin_amdgcn_rcpf(x)
#else
#define RCPF(x) (1.0f / (x))
#endif

// ---------------------------------------------------------------------------
// Pack kernel: Prec[i*N+n] = {sigma*log2e, sigma*mu*log2e, W, W*erev}
// (sigmoid(sigma*(v-mu)) = 1/(1 + 2^(B - A*v)) with A=sigma*log2e, B=sigma*mu*log2e)
// ---------------------------------------------------------------------------
__global__ __launch_bounds__(256) void pack_kernel(
    const float* __restrict__ mu, const float* __restrict__ sigma,
    const float* __restrict__ W, const float* __restrict__ erev,
    const float* __restrict__ smu, const float* __restrict__ ssigma,
    const float* __restrict__ sW, const float* __restrict__ serev,
    float4* __restrict__ Prec, float4* __restrict__ Psen) {
    int idx = blockIdx.x * blockDim.x + threadIdx.x;
    if (idx < Nn * Nn) {
        float s = sigma[idx], m = mu[idx], w = W[idx], e = erev[idx];
        Prec[idx] = make_float4(s * LOG2E, s * m * LOG2E, w, w * e);
    }
    int j = idx - Nn * Nn;
    if (j >= 0 && j < In * Nn) {
        float s = ssigma[j], m = smu[j], w = sW[j], e = serev[j];
        Psen[j] = make_float4(s * LOG2E, s * m * LOG2E, w, w * e);
    }
}

// ---------------------------------------------------------------------------
// Sensory kernel: per (b,n): sum_i sW*sig(...)*serev and sum_i sW*sig(...)
// Batch-tile 4 per block; 256 threads = one n-lane each. Grid = 256 blocks.
// ---------------------------------------------------------------------------
__global__ __launch_bounds__(256) void sensory_kernel(
    const float* __restrict__ inputs, const float* __restrict__ input_w,
    const float* __restrict__ input_b, const float4* __restrict__ Psen,
    float2* __restrict__ sens) {
    __shared__ float xs[4 * In];  // [bb][i]
    const int b0 = blockIdx.x * 4;
    const int tid = threadIdx.x;
    for (int k = tid; k < 4 * In; k += 256) {
        int bb = k >> 7, i = k & (In - 1);
        xs[k] = inputs[(b0 + bb) * In + i] * input_w[i] + input_b[i];
    }
    __syncthreads();
    const int n = tid;
    float num[4] = {0.f, 0.f, 0.f, 0.f};
    float den[4] = {0.f, 0.f, 0.f, 0.f};
    const float4* __restrict__ pp = Psen + n;
    for (int i = 0; i < In; ++i) {
        float4 p = pp[i * Nn];
#pragma unroll
        for (int bb = 0; bb < 4; ++bb) {
            float x = xs[bb * In + i];
            float e = EXP2F(p.y - p.x * x);
            float r = RCPF(1.0f + e);
            den[bb] += p.z * r;
            num[bb] += p.w * r;
        }
    }
#pragma unroll
    for (int bb = 0; bb < 4; ++bb)
        sens[(b0 + bb) * Nn + n] = make_float2(num[bb], den[bb]);
}

// ---------------------------------------------------------------------------
// Step kernel: one ODE unfold. Block = 8 batches x 128 n-outputs x 4 i-slices
// (512 threads). Grid = 128 b-tiles x 2 n-tiles = 256 blocks (1/CU, 8 waves).
// v tile (8x256 f32) staged in LDS; weights register-reused across 8 batches.
// ---------------------------------------------------------------------------
__global__ __launch_bounds__(512) void step_kernel(
    const float* __restrict__ vcur, const float4* __restrict__ Prec,
    const float2* __restrict__ sens, const float* __restrict__ vleak,
    const float* __restrict__ gleak, const float* __restrict__ cmt,
    float* __restrict__ vnext) {
    __shared__ float vt[8 * Nn];          // 8 KB   [bb][i]
    __shared__ float2 part[4 * 8 * 128];  // 32 KB  [slice][bb][n_l] (conflict-free)

    const int btile = blockIdx.x >> 1;
    const int n0 = (blockIdx.x & 1) * 128;
    const int b0 = btile * 8;
    const int tid = threadIdx.x;

    for (int k = tid; k < 8 * Nn; k += 512)
        vt[k] = vcur[(b0 + (k >> 8)) * Nn + (k & (Nn - 1))];
    __syncthreads();

    const int n_l = tid & 127;
    const int n = n0 + n_l;
    const int slice = tid >> 7;  // 0..3, covers i in [slice*64, slice*64+64)

    float num[8] = {0.f, 0.f, 0.f, 0.f, 0.f, 0.f, 0.f, 0.f};
    float den[8] = {0.f, 0.f, 0.f, 0.f, 0.f, 0.f, 0.f, 0.f};
    const float4* __restrict__ pp = Prec + n;
    const int i_end = slice * 64 + 64;
    for (int i = slice * 64; i < i_end; ++i) {
        float4 p = pp[i * Nn];  // Prec[i*N + n], coalesced across n-lanes
#pragma unroll
        for (int bb = 0; bb < 8; ++bb) {
            float v = vt[bb * Nn + i];  // LDS broadcast
            float e = EXP2F(p.y - p.x * v);
            float r = RCPF(1.0f + e);
            den[bb] += p.z * r;
            num[bb] += p.w * r;
        }
    }
#pragma unroll
    for (int bb = 0; bb < 8; ++bb)
        part[(slice * 8 + bb) * 128 + n_l] = make_float2(num[bb], den[bb]);
    __syncthreads();

    // Epilogue: reduce 4 slices, add sensory + leak terms, divide, store.
#pragma unroll
    for (int rep = 0; rep < 2; ++rep) {
        int q = tid + rep * 512;  // [0,1024) = 8 bb x 128 n_l
        int n_l2 = q & 127;
        int bb = q >> 7;
        int n2 = n0 + n_l2;
        int b = b0 + bb;
        float2 s0 = part[(0 * 8 + bb) * 128 + n_l2];
        float2 s1 = part[(1 * 8 + bb) * 128 + n_l2];
        float2 s2 = part[(2 * 8 + bb) * 128 + n_l2];
        float2 s3 = part[(3 * 8 + bb) * 128 + n_l2];
        float wn = (s0.x + s1.x) + (s2.x + s3.x);
        float wd = (s0.y + s1.y) + (s2.y + s3.y);
        float2 sv = sens[b * Nn + n2];
        wn += sv.x;
        wd += sv.y;
        float g = gleak[n2], c = cmt[n2];
        float vp = vt[bb * Nn + n2];
        float numerator = c * vp + g * vleak[n2] + wn;
        float denominator = c + g + wd;
        vnext[b * Nn + n2] = numerator / denominator;
    }
}

// ---------------------------------------------------------------------------
extern "C" void kernel_launch(void* const* d_in, const int* in_sizes, int n_in,
                              void* d_out, int out_size, void* d_ws, size_t ws_size,
                              hipStream_t stream) {
    const float* inputs   = (const float*)d_in[0];
    const float* state    = (const float*)d_in[1];
    const float* input_w  = (const float*)d_in[2];
    const float* input_b  = (const float*)d_in[3];
    const float* smu      = (const float*)d_in[4];
    const float* ssigma   = (const float*)d_in[5];
    const float* sW       = (const float*)d_in[6];
    const float* serev    = (const float*)d_in[7];
    const float* mu       = (const float*)d_in[8];
    const float* sigma    = (const float*)d_in[9];
    const float* W        = (const float*)d_in[10];
    const float* erev     = (const float*)d_in[11];
    const float* vleak    = (const float*)d_in[12];
    const float* gleak    = (const float*)d_in[13];
    const float* cmt      = (const float*)d_in[14];
    float* out = (float*)d_out;

    // Workspace layout (needs ~5.5 MiB)
    char* ws = (char*)d_ws;
    float4* Prec = (float4*)ws;                                   // N*N*16 = 1 MiB
    float4* Psen = (float4*)(ws + (size_t)Nn * Nn * 16);          // I*N*16 = 512 KiB
    float2* sens = (float2*)(ws + (size_t)(Nn * Nn + In * Nn) * 16);  // B*N*8 = 2 MiB
    float* vA = (float*)(ws + (size_t)(Nn * Nn + In * Nn) * 16 + (size_t)Bn * Nn * 8);
    float* vB = vA + (size_t)Bn * Nn;

    pack_kernel<<<(Nn * Nn + In * Nn + 255) / 256, 256, 0, stream>>>(
        mu, sigma, W, erev, smu, ssigma, sW, serev, Prec, Psen);

    sensory_kernel<<<Bn / 4, 256, 0, stream>>>(inputs, input_w, input_b, Psen, sens);

    const float* cur = state;
    for (int s = 0; s < UNFOLDS; ++s) {
        float* nxt = (s == UNFOLDS - 1) ? out : ((s & 1) ? vB : vA);
        step_kernel<<<256, 512, 0, stream>>>(cur, Prec, sens, vleak, gleak, cmt, nxt);
        cur = nxt;
    }
}